// Round 6
// baseline (260.827 us; speedup 1.0000x reference)
//
#include <hip/hip_runtime.h>

typedef __attribute__((ext_vector_type(8))) short short8;
typedef __attribute__((ext_vector_type(4))) short short4b;
typedef __attribute__((ext_vector_type(4))) float f32x4;

// fp32 -> bf16 bits, round-to-nearest-even (no NaN handling needed here)
static __device__ __forceinline__ short f2bf(float f) {
    unsigned u = __builtin_bit_cast(unsigned, f);
    u += 0x7FFFu + ((u >> 16) & 1u);
    return (short)(u >> 16);
}

// async global->LDS, 16 bytes per lane. lds base must be wave-uniform; HW adds lane*16.
static __device__ __forceinline__ void g2l16(const void* g, void* l) {
    __builtin_amdgcn_global_load_lds(
        (const __attribute__((address_space(1))) unsigned*)g,
        (__attribute__((address_space(3))) unsigned*)l, 16, 0, 0);
}

// ---------------------------------------------------------------------------
// elementwise fp32 -> bf16
__global__ void convert_x(const float* __restrict__ x, short* __restrict__ xb, int n4) {
    int i = blockIdx.x * blockDim.x + threadIdx.x;
    if (i >= n4) return;
    f32x4 v = *(const f32x4*)&x[(long)i * 4];
    short4b o;
    #pragma unroll
    for (int j = 0; j < 4; ++j) o[j] = f2bf(v[j]);
    *(short4b*)&xb[(long)i * 4] = o;
}

// ---------------------------------------------------------------------------
// W [K][N] fp32  ->  Wt [N][K] bf16   (64x64 LDS tile transpose)
__global__ void transpose_conv(const float* __restrict__ W, short* __restrict__ Wt,
                               int K, int N) {
    __shared__ float lds[64][65];
    const int t = threadIdx.x;
    const int n0 = blockIdx.x * 64, k0 = blockIdx.y * 64;
    const int rr = t >> 4, q4 = (t & 15) * 4;
    #pragma unroll
    for (int p = 0; p < 4; ++p) {
        int k = rr + p * 16;
        f32x4 v = *(const f32x4*)&W[(long)(k0 + k) * N + n0 + q4];
        #pragma unroll
        for (int j = 0; j < 4; ++j) lds[k][q4 + j] = v[j];
    }
    __syncthreads();
    #pragma unroll
    for (int p = 0; p < 4; ++p) {
        int nloc = rr + p * 16;
        short4b o;
        #pragma unroll
        for (int j = 0; j < 4; ++j) o[j] = f2bf(lds[q4 + j][nloc]);
        *(short4b*)&Wt[(long)(n0 + nloc) * K + k0 + q4] = o;
    }
}

// ---------------------------------------------------------------------------
// GEMM: C[M,N] = A[M,K] @ Bt[N,K]^T + bias.  A,Bt bf16 row-major.
// 128x128 tile, BK=32, 256 thr (4 waves, 2x2), 16x16x32 MFMA.
// QSCALE: scale (acc+bias) by 0.125 for cols < 1024 (pre-scales Q for attn).
template<int F32OUT, int QSCALE>
__global__ __launch_bounds__(256, 2)
void gemm_bt(const short* __restrict__ A, const short* __restrict__ Bt,
             const float* __restrict__ bias, void* __restrict__ C,
             int M, int N, int K) {
    __shared__ short lA[128 * 32];
    __shared__ short lB[128 * 32];
    const int t = threadIdx.x;
    const int lane = t & 63, w = t >> 6;
    const int m0 = blockIdx.y * 128, n0 = blockIdx.x * 128;
    const int lr = lane & 15, lk = lane >> 4;
    const int wr = w >> 1, wc = w & 1;

    f32x4 acc[4][4];
    #pragma unroll
    for (int i = 0; i < 4; ++i)
        #pragma unroll
        for (int j = 0; j < 4; ++j)
            #pragma unroll
            for (int e = 0; e < 4; ++e) acc[i][j][e] = 0.0f;

    const int nsteps = K >> 5;
    for (int kt = 0; kt < nsteps; ++kt) {
        const int kb = kt * 32;
        #pragma unroll
        for (int c = 0; c < 2; ++c) {
            int off  = c * 4096 + w * 1024;      // wave-uniform byte base in tile
            int offl = off + lane * 16;          // this lane's byte offset (for global addr)
            int ra = offl >> 6;                  // 64 B per LDS row (32 bf16)
            int ca = (offl & 63) >> 1;
            g2l16(A  + (long)(m0 + ra) * K + kb + ca, (short*)lA + (off >> 1));
            g2l16(Bt + (long)(n0 + ra) * K + kb + ca, (short*)lB + (off >> 1));
        }
        __syncthreads();
        short8 af[4], bf[4];
        #pragma unroll
        for (int m = 0; m < 4; ++m)
            af[m] = *(const short8*)&lA[(wr * 64 + m * 16 + lr) * 32 + lk * 8];
        #pragma unroll
        for (int n = 0; n < 4; ++n)
            bf[n] = *(const short8*)&lB[(wc * 64 + n * 16 + lr) * 32 + lk * 8];
        #pragma unroll
        for (int m = 0; m < 4; ++m)
            #pragma unroll
            for (int n = 0; n < 4; ++n)
                acc[m][n] = __builtin_amdgcn_mfma_f32_16x16x32_bf16(af[m], bf[n], acc[m][n], 0, 0, 0);
        __syncthreads();
    }

    #pragma unroll
    for (int n = 0; n < 4; ++n) {
        int col = n0 + wc * 64 + n * 16 + lr;
        float bb = bias[col];
        float sc = (QSCALE && col < 1024) ? 0.125f : 1.0f;
        #pragma unroll
        for (int m = 0; m < 4; ++m) {
            int rowb = m0 + wr * 64 + m * 16 + lk * 4;
            #pragma unroll
            for (int r = 0; r < 4; ++r) {
                float v = (acc[m][n][r] + bb) * sc;
                if (F32OUT) ((float*)C)[(long)(rowb + r) * N + col] = v;
                else        ((short*)C)[(long)(rowb + r) * N + col] = f2bf(v);
            }
        }
    }
}

// ---------------------------------------------------------------------------
// Vt[b,h,d,s] <- qkv[:, 2048 + h*64 + d]   (64x64 per-tile transpose)
__global__ void build_vt(const short* __restrict__ qkv, short* __restrict__ vt) {
    __shared__ short lds[64][72];
    const int t = threadIdx.x;
    const int st = blockIdx.x, bh = blockIdx.y;
    const int b = bh >> 4, h = bh & 15;
    const int s0 = st * 64;
    const int sr = t >> 3, c8 = (t & 7) * 8;
    #pragma unroll
    for (int p = 0; p < 2; ++p) {
        int s = sr + p * 32;
        short8 v = *(const short8*)&qkv[(long)(b * 2048 + s0 + s) * 3072 + 2048 + h * 64 + c8];
        *(short8*)&lds[s][c8] = v;
    }
    __syncthreads();
    #pragma unroll
    for (int p = 0; p < 2; ++p) {
        int d = sr + p * 32;
        short8 v;
        #pragma unroll
        for (int j = 0; j < 8; ++j) v[j] = lds[c8 + j][d];
        *(short8*)&vt[(long)(bh * 64 + d) * 2048 + s0 + c8] = v;
    }
}

// ---------------------------------------------------------------------------
// Flash causal attention, occupancy-first. QBLK=64 (4 waves x 16 q-rows),
// KVBLK=64, one block per (Q-tile, bh): grid 32x32 = 1024 blocks. LDS = 40KB
// -> 4 blocks/CU (16 waves/CU); dynamic dispatch backfills the causal
// imbalance (longest blocks launch first via Q = 31 - blockIdx.x).
// 2-phase double-buffer: stage(next) -> compute(cur) -> barrier.
// Only the last k-tile (kt == Q) crosses the diagonal -> causal compare only
// there; faithful ==0 -> FILL check everywhere. Q pre-scaled 0.125 in gemm1.
// LDS rows 128B; XOR swizzle slot' = slot ^ (row&7); lK/lV staged via
// linear-dest global_load_lds + pre-swizzled global source (rule #21).
__global__ __launch_bounds__(256, 4)
void attn_kernel(const short* __restrict__ qkv, const short* __restrict__ vt,
                 short* __restrict__ pre_o) {
    __shared__ short lK[2][64 * 64];        // [key][d]  8KB each
    __shared__ short lV[2][64 * 64];        // [d][key]  8KB each (swizzled)
    __shared__ short lP[4][16 * 64];        // per-wave P 2KB each (swizzled)
    const int t = threadIdx.x, lane = t & 63, w = t >> 6;
    const int lr = lane & 15, lk = lane >> 4;
    const int Q = 31 - blockIdx.x;          // longest-running blocks first
    const int bh = blockIdx.y;
    const int b = bh >> 4, h = bh & 15;
    const int q0 = Q * 64;
    const int nt = Q + 1;

    // per-lane staging geometry (two 4KB chunks per 8KB tile)
    int soff[2], sRow[2], sCol[2];
    #pragma unroll
    for (int c = 0; c < 2; ++c) {
        int off  = c * 4096 + w * 1024;
        int offl = off + lane * 16;
        int r    = offl >> 7;                          // row within 64-row tile
        soff[c]  = off >> 1;                           // short index of chunk base
        sRow[c]  = r;
        sCol[c]  = (((offl >> 4) & 7) ^ (r & 7)) * 8;  // logical bf16 col for this dest
    }

    // Q fragments (rows q0 + w*16 + lr, k = dk*32 + lk*8); pre-scaled by 1/8
    short8 aq[2];
    #pragma unroll
    for (int dk = 0; dk < 2; ++dk)
        aq[dk] = *(const short8*)&qkv[(long)(b * 2048 + q0 + w * 16 + lr) * 3072
                                      + h * 64 + dk * 32 + lk * 8];

    f32x4 accO[4];
    #pragma unroll
    for (int n = 0; n < 4; ++n)
        #pragma unroll
        for (int e = 0; e < 4; ++e) accO[n][e] = 0.0f;
    float mst[4], lst[4];
    #pragma unroll
    for (int r = 0; r < 4; ++r) { mst[r] = -1e30f; lst[r] = 0.0f; }

    // prologue: stage tile 0 into buf 0
    #pragma unroll
    for (int c = 0; c < 2; ++c) {
        g2l16(qkv + (long)(b * 2048 + sRow[c]) * 3072 + 1024 + h * 64 + sCol[c],
              &lK[0][soff[c]]);
        g2l16(vt + (long)(bh * 64 + sRow[c]) * 2048 + sCol[c],
              &lV[0][soff[c]]);
    }
    __syncthreads();

    #pragma unroll 1
    for (int kt = 0; kt < nt; ++kt) {
        const int cur = kt & 1;
        // stage next tile into the other buffer (flies during compute)
        if (kt + 1 < nt) {
            #pragma unroll
            for (int c = 0; c < 2; ++c) {
                g2l16(qkv + (long)(b * 2048 + (kt + 1) * 64 + sRow[c]) * 3072
                          + 1024 + h * 64 + sCol[c],
                      &lK[cur ^ 1][soff[c]]);
                g2l16(vt + (long)(bh * 64 + sRow[c]) * 2048 + (kt + 1) * 64 + sCol[c],
                      &lV[cur ^ 1][soff[c]]);
            }
        }

        // S = Q @ Ktile^T  (wave: 16 q-rows x 64 keys)
        f32x4 accS[4];
        #pragma unroll
        for (int n = 0; n < 4; ++n) {
            #pragma unroll
            for (int e = 0; e < 4; ++e) accS[n][e] = 0.0f;
            #pragma unroll
            for (int dk = 0; dk < 2; ++dk) {
                short8 bk = *(const short8*)((const char*)&lK[cur][0]
                             + (n * 16 + lr) * 128 + (((dk * 4 + lk) ^ (lr & 7)) << 4));
                accS[n] = __builtin_amdgcn_mfma_f32_16x16x32_bf16(aq[dk], bk, accS[n], 0, 0, 0);
            }
        }

        const bool diag = (kt == nt - 1);
        // online softmax (row = 16 consecutive lanes; cols = lane&15)
        #pragma unroll
        for (int r = 0; r < 4; ++r) {
            int qrow = q0 + w * 16 + lk * 4 + r;
            float sv[4];
            #pragma unroll
            for (int n = 0; n < 4; ++n) {
                float s = accS[n][r];
                if (diag) {
                    int key = kt * 64 + n * 16 + lr;
                    if (key > qrow || s == 0.0f) s = -10000.0f;
                } else {
                    if (s == 0.0f) s = -10000.0f;   // faithful zero-fill
                }
                sv[n] = s;
            }
            float mx = fmaxf(fmaxf(sv[0], sv[1]), fmaxf(sv[2], sv[3]));
            mx = fmaxf(mx, __shfl_xor(mx, 1));
            mx = fmaxf(mx, __shfl_xor(mx, 2));
            mx = fmaxf(mx, __shfl_xor(mx, 4));
            mx = fmaxf(mx, __shfl_xor(mx, 8));
            float mnew = fmaxf(mst[r], mx);
            float corr = __expf(mst[r] - mnew);
            mst[r] = mnew;
            float rs = 0.0f;
            #pragma unroll
            for (int n = 0; n < 4; ++n) { float p = __expf(sv[n] - mnew); sv[n] = p; rs += p; }
            rs += __shfl_xor(rs, 1);
            rs += __shfl_xor(rs, 2);
            rs += __shfl_xor(rs, 4);
            rs += __shfl_xor(rs, 8);
            lst[r] = lst[r] * corr + rs;
            #pragma unroll
            for (int n = 0; n < 4; ++n) accO[n][r] *= corr;
            // swizzled P write: row prr, col pc -> byte prr*128 + (pc*2 ^ ((prr&7)<<4))
            int prr = lk * 4 + r;
            int swz = (prr & 7) << 4;
            #pragma unroll
            for (int n = 0; n < 4; ++n) {
                int pc = n * 16 + lr;
                *(short*)((char*)&lP[w][0] + prr * 128 + ((pc * 2) ^ swz)) = f2bf(sv[n]);
            }
        }

        // O += P @ Vtile   (reads swizzled: slot' = slot ^ (row&7))
        short8 ap[2];
        #pragma unroll
        for (int kk = 0; kk < 2; ++kk)
            ap[kk] = *(const short8*)((const char*)&lP[w][0] + lr * 128
                                      + (((kk * 4 + lk) ^ (lr & 7)) << 4));
        #pragma unroll
        for (int n = 0; n < 4; ++n)
            #pragma unroll
            for (int kk = 0; kk < 2; ++kk) {
                short8 bv = *(const short8*)((const char*)&lV[cur][0]
                             + (n * 16 + lr) * 128 + (((kk * 4 + lk) ^ (lr & 7)) << 4));
                accO[n] = __builtin_amdgcn_mfma_f32_16x16x32_bf16(ap[kk], bv, accO[n], 0, 0, 0);
            }

        __syncthreads();   // drains vmcnt (next tile landed) + fences buffer reuse
    }

    // epilogue: O /= l, store bf16 into pre_o [4096][1024] (cols h*64+d)
    #pragma unroll
    for (int r = 0; r < 4; ++r) {
        int qrow = q0 + w * 16 + lk * 4 + r;
        float inv = 1.0f / lst[r];
        #pragma unroll
        for (int n = 0; n < 4; ++n)
            pre_o[(long)(b * 2048 + qrow) * 1024 + h * 64 + n * 16 + lr] =
                f2bf(accO[n][r] * inv);
    }
}

// ---------------------------------------------------------------------------
extern "C" void kernel_launch(void* const* d_in, const int* in_sizes, int n_in,
                              void* d_out, int out_size, void* d_ws, size_t ws_size,
                              hipStream_t stream) {
    const float* x    = (const float*)d_in[0];   // [2,2048,1024]
    const float* Wqkv = (const float*)d_in[1];   // [1024,3072]
    const float* bqkv = (const float*)d_in[2];   // [3072]
    const float* Wo   = (const float*)d_in[3];   // [1024,1024]
    const float* bo   = (const float*)d_in[4];   // [1024]
    float* out = (float*)d_out;                  // [2,2048,1024] fp32

    char* ws = (char*)d_ws;
    short* xb    = (short*)(ws);                       // 4096*1024   bf16 (8 MB)
    short* wqkvT = (short*)(ws + (8L  << 20));         // 3072*1024   (6 MB)
    short* woT   = (short*)(ws + (14L << 20));         // 1024*1024   (2 MB)
    short* qkv   = (short*)(ws + (16L << 20));         // 4096*3072   (24 MB)
    short* vt    = (short*)(ws + (40L << 20));         // 32*64*2048  (8 MB)
    short* preo  = (short*)(ws + (48L << 20));         // 4096*1024   (8 MB)

    convert_x<<<4096, 256, 0, stream>>>(x, xb, 4096 * 1024 / 4);
    transpose_conv<<<dim3(48, 16), 256, 0, stream>>>(Wqkv, wqkvT, 1024, 3072);
    transpose_conv<<<dim3(16, 16), 256, 0, stream>>>(Wo, woT, 1024, 1024);
    gemm_bt<0, 1><<<dim3(24, 32), 256, 0, stream>>>(xb, wqkvT, bqkv, qkv, 4096, 3072, 1024);
    build_vt<<<dim3(32, 32), 256, 0, stream>>>(qkv, vt);
    attn_kernel<<<dim3(32, 32), 256, 0, stream>>>(qkv, vt, preo);
    gemm_bt<1, 0><<<dim3(8, 32), 256, 0, stream>>>(preo, woT, bo, out, 4096, 1024, 1024);
}

// Round 7
// 242.896 us; speedup vs baseline: 1.0738x; 1.0738x over previous
//
#include <hip/hip_runtime.h>

typedef __attribute__((ext_vector_type(8))) short short8;
typedef __attribute__((ext_vector_type(4))) short short4b;
typedef __attribute__((ext_vector_type(4))) float f32x4;

// fp32 -> bf16 bits, round-to-nearest-even (no NaN handling needed here)
static __device__ __forceinline__ short f2bf(float f) {
    unsigned u = __builtin_bit_cast(unsigned, f);
    u += 0x7FFFu + ((u >> 16) & 1u);
    return (short)(u >> 16);
}

// async global->LDS, 16 bytes per lane. lds base must be wave-uniform; HW adds lane*16.
static __device__ __forceinline__ void g2l16(const void* g, void* l) {
    __builtin_amdgcn_global_load_lds(
        (const __attribute__((address_space(1))) unsigned*)g,
        (__attribute__((address_space(3))) unsigned*)l, 16, 0, 0);
}

// ---------------------------------------------------------------------------
// elementwise fp32 -> bf16
__global__ void convert_x(const float* __restrict__ x, short* __restrict__ xb, int n4) {
    int i = blockIdx.x * blockDim.x + threadIdx.x;
    if (i >= n4) return;
    f32x4 v = *(const f32x4*)&x[(long)i * 4];
    short4b o;
    #pragma unroll
    for (int j = 0; j < 4; ++j) o[j] = f2bf(v[j]);
    *(short4b*)&xb[(long)i * 4] = o;
}

// ---------------------------------------------------------------------------
// W [K][N] fp32  ->  Wt [N][K] bf16   (64x64 LDS tile transpose)
__global__ void transpose_conv(const float* __restrict__ W, short* __restrict__ Wt,
                               int K, int N) {
    __shared__ float lds[64][65];
    const int t = threadIdx.x;
    const int n0 = blockIdx.x * 64, k0 = blockIdx.y * 64;
    const int rr = t >> 4, q4 = (t & 15) * 4;
    #pragma unroll
    for (int p = 0; p < 4; ++p) {
        int k = rr + p * 16;
        f32x4 v = *(const f32x4*)&W[(long)(k0 + k) * N + n0 + q4];
        #pragma unroll
        for (int j = 0; j < 4; ++j) lds[k][q4 + j] = v[j];
    }
    __syncthreads();
    #pragma unroll
    for (int p = 0; p < 4; ++p) {
        int nloc = rr + p * 16;
        short4b o;
        #pragma unroll
        for (int j = 0; j < 4; ++j) o[j] = f2bf(lds[q4 + j][nloc]);
        *(short4b*)&Wt[(long)(n0 + nloc) * K + k0 + q4] = o;
    }
}

// ---------------------------------------------------------------------------
// GEMM: C[M,N] = A[M,K] @ Bt[N,K]^T + bias.  A,Bt bf16 row-major.
// 128x128 tile, BK=32, 256 thr (4 waves, 2x2), 16x16x32 MFMA.
// QSCALE: scale (acc+bias) by 0.125 for cols < 1024 (pre-scales Q for attn).
template<int F32OUT, int QSCALE>
__global__ __launch_bounds__(256, 2)
void gemm_bt(const short* __restrict__ A, const short* __restrict__ Bt,
             const float* __restrict__ bias, void* __restrict__ C,
             int M, int N, int K) {
    __shared__ short lA[128 * 32];
    __shared__ short lB[128 * 32];
    const int t = threadIdx.x;
    const int lane = t & 63, w = t >> 6;
    const int m0 = blockIdx.y * 128, n0 = blockIdx.x * 128;
    const int lr = lane & 15, lk = lane >> 4;
    const int wr = w >> 1, wc = w & 1;

    f32x4 acc[4][4];
    #pragma unroll
    for (int i = 0; i < 4; ++i)
        #pragma unroll
        for (int j = 0; j < 4; ++j)
            #pragma unroll
            for (int e = 0; e < 4; ++e) acc[i][j][e] = 0.0f;

    const int nsteps = K >> 5;
    for (int kt = 0; kt < nsteps; ++kt) {
        const int kb = kt * 32;
        #pragma unroll
        for (int c = 0; c < 2; ++c) {
            int off  = c * 4096 + w * 1024;      // wave-uniform byte base in tile
            int offl = off + lane * 16;          // this lane's byte offset (for global addr)
            int ra = offl >> 6;                  // 64 B per LDS row (32 bf16)
            int ca = (offl & 63) >> 1;
            g2l16(A  + (long)(m0 + ra) * K + kb + ca, (short*)lA + (off >> 1));
            g2l16(Bt + (long)(n0 + ra) * K + kb + ca, (short*)lB + (off >> 1));
        }
        __syncthreads();
        short8 af[4], bf[4];
        #pragma unroll
        for (int m = 0; m < 4; ++m)
            af[m] = *(const short8*)&lA[(wr * 64 + m * 16 + lr) * 32 + lk * 8];
        #pragma unroll
        for (int n = 0; n < 4; ++n)
            bf[n] = *(const short8*)&lB[(wc * 64 + n * 16 + lr) * 32 + lk * 8];
        #pragma unroll
        for (int m = 0; m < 4; ++m)
            #pragma unroll
            for (int n = 0; n < 4; ++n)
                acc[m][n] = __builtin_amdgcn_mfma_f32_16x16x32_bf16(af[m], bf[n], acc[m][n], 0, 0, 0);
        __syncthreads();
    }

    #pragma unroll
    for (int n = 0; n < 4; ++n) {
        int col = n0 + wc * 64 + n * 16 + lr;
        float bb = bias[col];
        float sc = (QSCALE && col < 1024) ? 0.125f : 1.0f;
        #pragma unroll
        for (int m = 0; m < 4; ++m) {
            int rowb = m0 + wr * 64 + m * 16 + lk * 4;
            #pragma unroll
            for (int r = 0; r < 4; ++r) {
                float v = (acc[m][n][r] + bb) * sc;
                if (F32OUT) ((float*)C)[(long)(rowb + r) * N + col] = v;
                else        ((short*)C)[(long)(rowb + r) * N + col] = f2bf(v);
            }
        }
    }
}

// ---------------------------------------------------------------------------
// Vt[b,h,d,s] <- qkv[:, 2048 + h*64 + d]   (64x64 per-tile transpose)
__global__ void build_vt(const short* __restrict__ qkv, short* __restrict__ vt) {
    __shared__ short lds[64][72];
    const int t = threadIdx.x;
    const int st = blockIdx.x, bh = blockIdx.y;
    const int b = bh >> 4, h = bh & 15;
    const int s0 = st * 64;
    const int sr = t >> 3, c8 = (t & 7) * 8;
    #pragma unroll
    for (int p = 0; p < 2; ++p) {
        int s = sr + p * 32;
        short8 v = *(const short8*)&qkv[(long)(b * 2048 + s0 + s) * 3072 + 2048 + h * 64 + c8];
        *(short8*)&lds[s][c8] = v;
    }
    __syncthreads();
    #pragma unroll
    for (int p = 0; p < 2; ++p) {
        int d = sr + p * 32;
        short8 v;
        #pragma unroll
        for (int j = 0; j < 8; ++j) v[j] = lds[c8 + j][d];
        *(short8*)&vt[(long)(bh * 64 + d) * 2048 + s0 + c8] = v;
    }
}

// ---------------------------------------------------------------------------
// Flash causal attention with KV split (flash-decoding style) for balance +
// occupancy. QBLK=64 (4 waves x 16 q-rows), KVBLK=64, LDS 40KB -> 4 blocks/CU
// (16 waves/CU). blockIdx.x = slice in [0,44), longest-first:
//   x<10   : single Q = 19-x        (key tiles [0, Q+1))
//   10..33 : i=x-10; Q = 31-(i>>1), half = i&1, h0=(Q+1)>>1
//            half0 -> [0,h0) (never diagonal), half1 -> [h0,Q+1)
//   x>=34  : single Q = 43-x
// 1408 blocks > 1024 resident slots -> backfill absorbs imbalance.
// Singles write preo directly; halves write unnormalized fp32 partials
// (U, m, l) into dead workspace; attn_combine merges them.
// LDS rows 128B; XOR swizzle slot' = slot ^ (row&7); lK/lV staged via
// linear-dest global_load_lds + pre-swizzled global source (rule #21).
__global__ __launch_bounds__(256, 4)
void attn_kernel(const short* __restrict__ qkv, const short* __restrict__ vt,
                 short* __restrict__ pre_o, float* __restrict__ pO,
                 float* __restrict__ pML) {
    __shared__ short lK[2][64 * 64];        // [key][d]  8KB each
    __shared__ short lV[2][64 * 64];        // [d][key]  8KB each (swizzled)
    __shared__ short lP[4][16 * 64];        // per-wave P 2KB each (swizzled)
    const int t = threadIdx.x, lane = t & 63, w = t >> 6;
    const int lr = lane & 15, lk = lane >> 4;
    const int x = blockIdx.x, bh = blockIdx.y;
    const int b = bh >> 4, h = bh & 15;

    int Q, kt0, kt1, half = -1;
    if (x < 10)      { Q = 19 - x; kt0 = 0; kt1 = Q + 1; }
    else if (x < 34) { int i = x - 10; Q = 31 - (i >> 1); half = i & 1;
                       int h0 = (Q + 1) >> 1;
                       kt0 = half ? h0 : 0; kt1 = half ? (Q + 1) : h0; }
    else             { Q = 43 - x; kt0 = 0; kt1 = Q + 1; }
    const int q0 = Q * 64;

    // per-lane staging geometry (two 4KB chunks per 8KB tile)
    int soff[2], sRow[2], sCol[2];
    #pragma unroll
    for (int c = 0; c < 2; ++c) {
        int off  = c * 4096 + w * 1024;
        int offl = off + lane * 16;
        int r    = offl >> 7;                          // row within 64-row tile
        soff[c]  = off >> 1;                           // short index of chunk base
        sRow[c]  = r;
        sCol[c]  = (((offl >> 4) & 7) ^ (r & 7)) * 8;  // logical bf16 col for this dest
    }

    // Q fragments (rows q0 + w*16 + lr, k = dk*32 + lk*8); pre-scaled by 1/8
    short8 aq[2];
    #pragma unroll
    for (int dk = 0; dk < 2; ++dk)
        aq[dk] = *(const short8*)&qkv[(long)(b * 2048 + q0 + w * 16 + lr) * 3072
                                      + h * 64 + dk * 32 + lk * 8];

    f32x4 accO[4];
    #pragma unroll
    for (int n = 0; n < 4; ++n)
        #pragma unroll
        for (int e = 0; e < 4; ++e) accO[n][e] = 0.0f;
    float mst[4], lst[4];
    #pragma unroll
    for (int r = 0; r < 4; ++r) { mst[r] = -1e30f; lst[r] = 0.0f; }

    // prologue: stage tile kt0 into buf 0
    #pragma unroll
    for (int c = 0; c < 2; ++c) {
        g2l16(qkv + (long)(b * 2048 + kt0 * 64 + sRow[c]) * 3072 + 1024 + h * 64 + sCol[c],
              &lK[0][soff[c]]);
        g2l16(vt + (long)(bh * 64 + sRow[c]) * 2048 + kt0 * 64 + sCol[c],
              &lV[0][soff[c]]);
    }
    __syncthreads();

    #pragma unroll 1
    for (int kt = kt0; kt < kt1; ++kt) {
        const int cur = (kt - kt0) & 1;
        // stage next tile into the other buffer (flies during compute)
        if (kt + 1 < kt1) {
            #pragma unroll
            for (int c = 0; c < 2; ++c) {
                g2l16(qkv + (long)(b * 2048 + (kt + 1) * 64 + sRow[c]) * 3072
                          + 1024 + h * 64 + sCol[c],
                      &lK[cur ^ 1][soff[c]]);
                g2l16(vt + (long)(bh * 64 + sRow[c]) * 2048 + (kt + 1) * 64 + sCol[c],
                      &lV[cur ^ 1][soff[c]]);
            }
        }

        // S = Q @ Ktile^T  (wave: 16 q-rows x 64 keys)
        f32x4 accS[4];
        #pragma unroll
        for (int n = 0; n < 4; ++n) {
            #pragma unroll
            for (int e = 0; e < 4; ++e) accS[n][e] = 0.0f;
            #pragma unroll
            for (int dk = 0; dk < 2; ++dk) {
                short8 bk = *(const short8*)((const char*)&lK[cur][0]
                             + (n * 16 + lr) * 128 + (((dk * 4 + lk) ^ (lr & 7)) << 4));
                accS[n] = __builtin_amdgcn_mfma_f32_16x16x32_bf16(aq[dk], bk, accS[n], 0, 0, 0);
            }
        }

        const bool diag = (kt == Q);   // only the true diagonal tile masks keys
        // online softmax (row = 16 consecutive lanes; cols = lane&15)
        #pragma unroll
        for (int r = 0; r < 4; ++r) {
            int qrow = q0 + w * 16 + lk * 4 + r;
            float sv[4];
            #pragma unroll
            for (int n = 0; n < 4; ++n) {
                float s = accS[n][r];
                if (diag) {
                    int key = kt * 64 + n * 16 + lr;
                    if (key > qrow || s == 0.0f) s = -10000.0f;
                } else {
                    if (s == 0.0f) s = -10000.0f;   // faithful zero-fill
                }
                sv[n] = s;
            }
            float mx = fmaxf(fmaxf(sv[0], sv[1]), fmaxf(sv[2], sv[3]));
            mx = fmaxf(mx, __shfl_xor(mx, 1));
            mx = fmaxf(mx, __shfl_xor(mx, 2));
            mx = fmaxf(mx, __shfl_xor(mx, 4));
            mx = fmaxf(mx, __shfl_xor(mx, 8));
            float mnew = fmaxf(mst[r], mx);
            float corr = __expf(mst[r] - mnew);
            mst[r] = mnew;
            float rs = 0.0f;
            #pragma unroll
            for (int n = 0; n < 4; ++n) { float p = __expf(sv[n] - mnew); sv[n] = p; rs += p; }
            rs += __shfl_xor(rs, 1);
            rs += __shfl_xor(rs, 2);
            rs += __shfl_xor(rs, 4);
            rs += __shfl_xor(rs, 8);
            lst[r] = lst[r] * corr + rs;
            #pragma unroll
            for (int n = 0; n < 4; ++n) accO[n][r] *= corr;
            // swizzled P write: row prr, col pc -> byte prr*128 + (pc*2 ^ ((prr&7)<<4))
            int prr = lk * 4 + r;
            int swz = (prr & 7) << 4;
            #pragma unroll
            for (int n = 0; n < 4; ++n) {
                int pc = n * 16 + lr;
                *(short*)((char*)&lP[w][0] + prr * 128 + ((pc * 2) ^ swz)) = f2bf(sv[n]);
            }
        }

        // O += P @ Vtile   (reads swizzled: slot' = slot ^ (row&7))
        short8 ap[2];
        #pragma unroll
        for (int kk = 0; kk < 2; ++kk)
            ap[kk] = *(const short8*)((const char*)&lP[w][0] + lr * 128
                                      + (((kk * 4 + lk) ^ (lr & 7)) << 4));
        #pragma unroll
        for (int n = 0; n < 4; ++n)
            #pragma unroll
            for (int kk = 0; kk < 2; ++kk) {
                short8 bv = *(const short8*)((const char*)&lV[cur][0]
                             + (n * 16 + lr) * 128 + (((kk * 4 + lk) ^ (lr & 7)) << 4));
                accO[n] = __builtin_amdgcn_mfma_f32_16x16x32_bf16(ap[kk], bv, accO[n], 0, 0, 0);
            }

        __syncthreads();   // drains vmcnt (next tile landed) + fences buffer reuse
    }

    if (half < 0) {
        // single: normalize and store bf16 into pre_o [4096][1024]
        #pragma unroll
        for (int r = 0; r < 4; ++r) {
            int qrow = q0 + w * 16 + lk * 4 + r;
            float inv = 1.0f / lst[r];
            #pragma unroll
            for (int n = 0; n < 4; ++n)
                pre_o[(long)(b * 2048 + qrow) * 1024 + h * 64 + n * 16 + lr] =
                    f2bf(accO[n][r] * inv);
        }
    } else {
        // split half: write unnormalized partials (fp32 U, m, l)
        const int g2 = ((Q - 20) * 32 + bh) * 2 + half;
        float* U  = pO  + (long)g2 * 4096;
        float* ML = pML + (long)g2 * 128;
        #pragma unroll
        for (int r = 0; r < 4; ++r) {
            int row = w * 16 + lk * 4 + r;
            #pragma unroll
            for (int n = 0; n < 4; ++n)
                U[row * 64 + n * 16 + lr] = accO[n][r];
            if (lr == 0) { ML[row * 2] = mst[r]; ML[row * 2 + 1] = lst[r]; }
        }
    }
}

// ---------------------------------------------------------------------------
// merge the two KV-halves for Q-tiles 20..31: standard flash combine.
__global__ __launch_bounds__(256)
void attn_combine(const float* __restrict__ pO, const float* __restrict__ pML,
                  short* __restrict__ pre_o) {
    const int g = blockIdx.x;                 // 0..383
    const int Q = 20 + (g >> 5), bh = g & 31, b = bh >> 4, h = bh & 15;
    const int t = threadIdx.x;
    const int row = t >> 2, d0 = (t & 3) * 16;
    const float* ML0 = pML + ((long)(g * 2 + 0)) * 128 + row * 2;
    const float* ML1 = pML + ((long)(g * 2 + 1)) * 128 + row * 2;
    float m0 = ML0[0], l0 = ML0[1], m1 = ML1[0], l1 = ML1[1];
    float m = fmaxf(m0, m1);
    float e0 = __expf(m0 - m), e1 = __expf(m1 - m);
    float inv = 1.0f / (l0 * e0 + l1 * e1);
    const float* U0 = pO + ((long)(g * 2 + 0)) * 4096 + row * 64 + d0;
    const float* U1 = pO + ((long)(g * 2 + 1)) * 4096 + row * 64 + d0;
    long out = ((long)(b * 2048 + Q * 64 + row)) * 1024 + h * 64 + d0;
    #pragma unroll
    for (int j = 0; j < 16; j += 4) {
        f32x4 a = *(const f32x4*)&U0[j];
        f32x4 c = *(const f32x4*)&U1[j];
        #pragma unroll
        for (int e = 0; e < 4; ++e)
            pre_o[out + j + e] = f2bf((a[e] * e0 + c[e] * e1) * inv);
    }
}

// ---------------------------------------------------------------------------
extern "C" void kernel_launch(void* const* d_in, const int* in_sizes, int n_in,
                              void* d_out, int out_size, void* d_ws, size_t ws_size,
                              hipStream_t stream) {
    const float* x    = (const float*)d_in[0];   // [2,2048,1024]
    const float* Wqkv = (const float*)d_in[1];   // [1024,3072]
    const float* bqkv = (const float*)d_in[2];   // [3072]
    const float* Wo   = (const float*)d_in[3];   // [1024,1024]
    const float* bo   = (const float*)d_in[4];   // [1024]
    float* out = (float*)d_out;                  // [2,2048,1024] fp32

    char* ws = (char*)d_ws;
    short* xb    = (short*)(ws);                       // 4096*1024   bf16 (8 MB)
    short* wqkvT = (short*)(ws + (8L  << 20));         // 3072*1024   (6 MB)
    short* woT   = (short*)(ws + (14L << 20));         // 1024*1024   (2 MB)
    short* qkv   = (short*)(ws + (16L << 20));         // 4096*3072   (24 MB)
    short* vt    = (short*)(ws + (40L << 20));         // 32*64*2048  (8 MB)
    short* preo  = (short*)(ws + (48L << 20));         // 4096*1024   (8 MB)
    // split-K partials overlay xb+wqkvT (dead during attention):
    float* pO    = (float*)(ws);                       // 384*2*4096 f32 (12.6 MB)
    float* pML   = (float*)(ws + 12779520L);           // 384*2*64*2 f32 (0.4 MB) -> ends < 14 MB

    convert_x<<<4096, 256, 0, stream>>>(x, xb, 4096 * 1024 / 4);
    transpose_conv<<<dim3(48, 16), 256, 0, stream>>>(Wqkv, wqkvT, 1024, 3072);
    transpose_conv<<<dim3(16, 16), 256, 0, stream>>>(Wo, woT, 1024, 1024);
    gemm_bt<0, 1><<<dim3(24, 32), 256, 0, stream>>>(xb, wqkvT, bqkv, qkv, 4096, 3072, 1024);
    build_vt<<<dim3(32, 32), 256, 0, stream>>>(qkv, vt);
    attn_kernel<<<dim3(44, 32), 256, 0, stream>>>(qkv, vt, preo, pO, pML);
    attn_combine<<<384, 256, 0, stream>>>(pO, pML, preo);
    gemm_bt<1, 0><<<dim3(8, 32), 256, 0, stream>>>(preo, woT, bo, out, 4096, 1024, 1024);
}

// Round 8
// 227.504 us; speedup vs baseline: 1.1465x; 1.0677x over previous
//
#include <hip/hip_runtime.h>

typedef __attribute__((ext_vector_type(8))) short short8;
typedef __attribute__((ext_vector_type(4))) short short4b;
typedef __attribute__((ext_vector_type(4))) float f32x4;

// fp32 -> bf16 bits, round-to-nearest-even (no NaN handling needed here)
static __device__ __forceinline__ short f2bf(float f) {
    unsigned u = __builtin_bit_cast(unsigned, f);
    u += 0x7FFFu + ((u >> 16) & 1u);
    return (short)(u >> 16);
}

// async global->LDS, 16 bytes per lane. lds base must be wave-uniform; HW adds lane*16.
static __device__ __forceinline__ void g2l16(const void* g, void* l) {
    __builtin_amdgcn_global_load_lds(
        (const __attribute__((address_space(1))) unsigned*)g,
        (__attribute__((address_space(3))) unsigned*)l, 16, 0, 0);
}

// ---------------------------------------------------------------------------
// elementwise fp32 -> bf16
__global__ void convert_x(const float* __restrict__ x, short* __restrict__ xb, int n4) {
    int i = blockIdx.x * blockDim.x + threadIdx.x;
    if (i >= n4) return;
    f32x4 v = *(const f32x4*)&x[(long)i * 4];
    short4b o;
    #pragma unroll
    for (int j = 0; j < 4; ++j) o[j] = f2bf(v[j]);
    *(short4b*)&xb[(long)i * 4] = o;
}

// ---------------------------------------------------------------------------
// W [K][N] fp32  ->  Wt [N][K] bf16   (64x64 LDS tile transpose)
__global__ void transpose_conv(const float* __restrict__ W, short* __restrict__ Wt,
                               int K, int N) {
    __shared__ float lds[64][65];
    const int t = threadIdx.x;
    const int n0 = blockIdx.x * 64, k0 = blockIdx.y * 64;
    const int rr = t >> 4, q4 = (t & 15) * 4;
    #pragma unroll
    for (int p = 0; p < 4; ++p) {
        int k = rr + p * 16;
        f32x4 v = *(const f32x4*)&W[(long)(k0 + k) * N + n0 + q4];
        #pragma unroll
        for (int j = 0; j < 4; ++j) lds[k][q4 + j] = v[j];
    }
    __syncthreads();
    #pragma unroll
    for (int p = 0; p < 4; ++p) {
        int nloc = rr + p * 16;
        short4b o;
        #pragma unroll
        for (int j = 0; j < 4; ++j) o[j] = f2bf(lds[q4 + j][nloc]);
        *(short4b*)&Wt[(long)(n0 + nloc) * K + k0 + q4] = o;
    }
}

// ---------------------------------------------------------------------------
// GEMM: C[M,N] = A[M,K] @ Bt[N,K]^T + bias.  A,Bt bf16 row-major.
// 128x128 tile, BK=32, 256 thr (4 waves, 2x2), 16x16x32 MFMA.
// QSCALE: scale (acc+bias) by 0.125 for cols < 1024 (pre-scales Q for attn).
template<int F32OUT, int QSCALE>
__global__ __launch_bounds__(256, 2)
void gemm_bt(const short* __restrict__ A, const short* __restrict__ Bt,
             const float* __restrict__ bias, void* __restrict__ C,
             int M, int N, int K) {
    __shared__ short lA[128 * 32];
    __shared__ short lB[128 * 32];
    const int t = threadIdx.x;
    const int lane = t & 63, w = t >> 6;
    const int m0 = blockIdx.y * 128, n0 = blockIdx.x * 128;
    const int lr = lane & 15, lk = lane >> 4;
    const int wr = w >> 1, wc = w & 1;

    f32x4 acc[4][4];
    #pragma unroll
    for (int i = 0; i < 4; ++i)
        #pragma unroll
        for (int j = 0; j < 4; ++j)
            #pragma unroll
            for (int e = 0; e < 4; ++e) acc[i][j][e] = 0.0f;

    const int nsteps = K >> 5;
    for (int kt = 0; kt < nsteps; ++kt) {
        const int kb = kt * 32;
        #pragma unroll
        for (int c = 0; c < 2; ++c) {
            int off  = c * 4096 + w * 1024;      // wave-uniform byte base in tile
            int offl = off + lane * 16;          // this lane's byte offset (for global addr)
            int ra = offl >> 6;                  // 64 B per LDS row (32 bf16)
            int ca = (offl & 63) >> 1;
            g2l16(A  + (long)(m0 + ra) * K + kb + ca, (short*)lA + (off >> 1));
            g2l16(Bt + (long)(n0 + ra) * K + kb + ca, (short*)lB + (off >> 1));
        }
        __syncthreads();
        short8 af[4], bf[4];
        #pragma unroll
        for (int m = 0; m < 4; ++m)
            af[m] = *(const short8*)&lA[(wr * 64 + m * 16 + lr) * 32 + lk * 8];
        #pragma unroll
        for (int n = 0; n < 4; ++n)
            bf[n] = *(const short8*)&lB[(wc * 64 + n * 16 + lr) * 32 + lk * 8];
        #pragma unroll
        for (int m = 0; m < 4; ++m)
            #pragma unroll
            for (int n = 0; n < 4; ++n)
                acc[m][n] = __builtin_amdgcn_mfma_f32_16x16x32_bf16(af[m], bf[n], acc[m][n], 0, 0, 0);
        __syncthreads();
    }

    #pragma unroll
    for (int n = 0; n < 4; ++n) {
        int col = n0 + wc * 64 + n * 16 + lr;
        float bb = bias[col];
        float sc = (QSCALE && col < 1024) ? 0.125f : 1.0f;
        #pragma unroll
        for (int m = 0; m < 4; ++m) {
            int rowb = m0 + wr * 64 + m * 16 + lk * 4;
            #pragma unroll
            for (int r = 0; r < 4; ++r) {
                float v = (acc[m][n][r] + bb) * sc;
                if (F32OUT) ((float*)C)[(long)(rowb + r) * N + col] = v;
                else        ((short*)C)[(long)(rowb + r) * N + col] = f2bf(v);
            }
        }
    }
}

// ---------------------------------------------------------------------------
// Vt[b,h,d,s] <- qkv[:, 2048 + h*64 + d]   (64x64 per-tile transpose)
__global__ void build_vt(const short* __restrict__ qkv, short* __restrict__ vt) {
    __shared__ short lds[64][72];
    const int t = threadIdx.x;
    const int st = blockIdx.x, bh = blockIdx.y;
    const int b = bh >> 4, h = bh & 15;
    const int s0 = st * 64;
    const int sr = t >> 3, c8 = (t & 7) * 8;
    #pragma unroll
    for (int p = 0; p < 2; ++p) {
        int s = sr + p * 32;
        short8 v = *(const short8*)&qkv[(long)(b * 2048 + s0 + s) * 3072 + 2048 + h * 64 + c8];
        *(short8*)&lds[s][c8] = v;
    }
    __syncthreads();
    #pragma unroll
    for (int p = 0; p < 2; ++p) {
        int d = sr + p * 32;
        short8 v;
        #pragma unroll
        for (int j = 0; j < 8; ++j) v[j] = lds[c8 + j][d];
        *(short8*)&vt[(long)(bh * 64 + d) * 2048 + s0 + c8] = v;
    }
}

// ---------------------------------------------------------------------------
// Flash causal attention with KV split, GLOBAL longest-first dispatch.
// grid = (bh=32 fastest, rank=44): HIP dispatches linear x-fastest, so all 32
// bh of rank 0 (the longest slices) launch before rank 1, etc. Slice table
// sorted by descending length -> the 1024 resident slots take the 32 longest
// ranks; backfill jobs are short (<=11 tiles) -> minimal tail.
// QBLK=64 (4 waves x 16 q-rows), KVBLK=64, LDS 40KB -> 4 blocks/CU.
// Singles write preo; halves write fp32 partials (U,m,l); combine merges.
__device__ const signed char rQ[44]  = {19,18,17,16,15, 31,31,30, 14,30,29,29,28,
                                        13,28,27,27,26, 12,26,25,25,24, 11,24,23,23,22,
                                        10,22,21,21,20, 9,20, 8,7,6,5,4,3,2,1,0};
__device__ const signed char rK0[44] = { 0, 0, 0, 0, 0,  0,16,15,  0, 0, 0,15,14,
                                          0, 0, 0,14,13,  0, 0, 0,13,12,  0, 0, 0,12,11,
                                          0, 0, 0,11,10,  0, 0, 0,0,0,0,0,0,0,0,0};
__device__ const signed char rK1[44] = {20,19,18,17,16, 16,32,31, 15,15,15,30,29,
                                        14,14,14,28,27, 13,13,13,26,25, 12,12,12,24,23,
                                        11,11,11,22,21, 10,10, 9,8,7,6,5,4,3,2,1};
__device__ const signed char rHf[44] = {-1,-1,-1,-1,-1,  0, 1, 1, -1, 0, 0, 1, 1,
                                        -1, 0, 0, 1, 1, -1, 0, 0, 1, 1, -1, 0, 0, 1, 1,
                                        -1, 0, 0, 1, 1, -1, 0, -1,-1,-1,-1,-1,-1,-1,-1,-1};

__global__ __launch_bounds__(256, 4)
void attn_kernel(const short* __restrict__ qkv, const short* __restrict__ vt,
                 short* __restrict__ pre_o, float* __restrict__ pO,
                 float* __restrict__ pML) {
    __shared__ short lK[2][64 * 64];        // [key][d]  8KB each
    __shared__ short lV[2][64 * 64];        // [d][key]  8KB each (swizzled)
    __shared__ short lP[4][16 * 64];        // per-wave P 2KB each (swizzled)
    const int t = threadIdx.x, lane = t & 63, w = t >> 6;
    const int lr = lane & 15, lk = lane >> 4;
    const int bh = blockIdx.x, rank = blockIdx.y;
    const int b = bh >> 4, h = bh & 15;

    const int Q    = rQ[rank];
    const int kt0  = rK0[rank];
    const int kt1  = rK1[rank];
    const int half = rHf[rank];
    const int q0 = Q * 64;

    // per-lane staging geometry (two 4KB chunks per 8KB tile)
    int soff[2], sRow[2], sCol[2];
    #pragma unroll
    for (int c = 0; c < 2; ++c) {
        int off  = c * 4096 + w * 1024;
        int offl = off + lane * 16;
        int r    = offl >> 7;                          // row within 64-row tile
        soff[c]  = off >> 1;                           // short index of chunk base
        sRow[c]  = r;
        sCol[c]  = (((offl >> 4) & 7) ^ (r & 7)) * 8;  // logical bf16 col for this dest
    }

    // Q fragments (rows q0 + w*16 + lr, k = dk*32 + lk*8); pre-scaled by 1/8
    short8 aq[2];
    #pragma unroll
    for (int dk = 0; dk < 2; ++dk)
        aq[dk] = *(const short8*)&qkv[(long)(b * 2048 + q0 + w * 16 + lr) * 3072
                                      + h * 64 + dk * 32 + lk * 8];

    f32x4 accO[4];
    #pragma unroll
    for (int n = 0; n < 4; ++n)
        #pragma unroll
        for (int e = 0; e < 4; ++e) accO[n][e] = 0.0f;
    float mst[4], lst[4];
    #pragma unroll
    for (int r = 0; r < 4; ++r) { mst[r] = -1e30f; lst[r] = 0.0f; }

    // prologue: stage tile kt0 into buf 0
    #pragma unroll
    for (int c = 0; c < 2; ++c) {
        g2l16(qkv + (long)(b * 2048 + kt0 * 64 + sRow[c]) * 3072 + 1024 + h * 64 + sCol[c],
              &lK[0][soff[c]]);
        g2l16(vt + (long)(bh * 64 + sRow[c]) * 2048 + kt0 * 64 + sCol[c],
              &lV[0][soff[c]]);
    }
    __syncthreads();

    #pragma unroll 1
    for (int kt = kt0; kt < kt1; ++kt) {
        const int cur = (kt - kt0) & 1;
        // stage next tile into the other buffer (flies during compute)
        if (kt + 1 < kt1) {
            #pragma unroll
            for (int c = 0; c < 2; ++c) {
                g2l16(qkv + (long)(b * 2048 + (kt + 1) * 64 + sRow[c]) * 3072
                          + 1024 + h * 64 + sCol[c],
                      &lK[cur ^ 1][soff[c]]);
                g2l16(vt + (long)(bh * 64 + sRow[c]) * 2048 + (kt + 1) * 64 + sCol[c],
                      &lV[cur ^ 1][soff[c]]);
            }
        }

        // S = Q @ Ktile^T  (wave: 16 q-rows x 64 keys)
        f32x4 accS[4];
        #pragma unroll
        for (int n = 0; n < 4; ++n) {
            #pragma unroll
            for (int e = 0; e < 4; ++e) accS[n][e] = 0.0f;
            #pragma unroll
            for (int dk = 0; dk < 2; ++dk) {
                short8 bk = *(const short8*)((const char*)&lK[cur][0]
                             + (n * 16 + lr) * 128 + (((dk * 4 + lk) ^ (lr & 7)) << 4));
                accS[n] = __builtin_amdgcn_mfma_f32_16x16x32_bf16(aq[dk], bk, accS[n], 0, 0, 0);
            }
        }

        const bool diag = (kt == Q);   // only the true diagonal tile masks keys
        // online softmax (row = 16 consecutive lanes; cols = lane&15)
        #pragma unroll
        for (int r = 0; r < 4; ++r) {
            int qrow = q0 + w * 16 + lk * 4 + r;
            float sv[4];
            #pragma unroll
            for (int n = 0; n < 4; ++n) {
                float s = accS[n][r];
                if (diag) {
                    int key = kt * 64 + n * 16 + lr;
                    if (key > qrow || s == 0.0f) s = -10000.0f;
                } else {
                    if (s == 0.0f) s = -10000.0f;   // faithful zero-fill
                }
                sv[n] = s;
            }
            float mx = fmaxf(fmaxf(sv[0], sv[1]), fmaxf(sv[2], sv[3]));
            mx = fmaxf(mx, __shfl_xor(mx, 1));
            mx = fmaxf(mx, __shfl_xor(mx, 2));
            mx = fmaxf(mx, __shfl_xor(mx, 4));
            mx = fmaxf(mx, __shfl_xor(mx, 8));
            float mnew = fmaxf(mst[r], mx);
            float corr = __expf(mst[r] - mnew);
            mst[r] = mnew;
            float rs = 0.0f;
            #pragma unroll
            for (int n = 0; n < 4; ++n) { float p = __expf(sv[n] - mnew); sv[n] = p; rs += p; }
            rs += __shfl_xor(rs, 1);
            rs += __shfl_xor(rs, 2);
            rs += __shfl_xor(rs, 4);
            rs += __shfl_xor(rs, 8);
            lst[r] = lst[r] * corr + rs;
            #pragma unroll
            for (int n = 0; n < 4; ++n) accO[n][r] *= corr;
            // swizzled P write: row prr, col pc -> byte prr*128 + (pc*2 ^ ((prr&7)<<4))
            int prr = lk * 4 + r;
            int swz = (prr & 7) << 4;
            #pragma unroll
            for (int n = 0; n < 4; ++n) {
                int pc = n * 16 + lr;
                *(short*)((char*)&lP[w][0] + prr * 128 + ((pc * 2) ^ swz)) = f2bf(sv[n]);
            }
        }

        // O += P @ Vtile   (reads swizzled: slot' = slot ^ (row&7))
        short8 ap[2];
        #pragma unroll
        for (int kk = 0; kk < 2; ++kk)
            ap[kk] = *(const short8*)((const char*)&lP[w][0] + lr * 128
                                      + (((kk * 4 + lk) ^ (lr & 7)) << 4));
        #pragma unroll
        for (int n = 0; n < 4; ++n)
            #pragma unroll
            for (int kk = 0; kk < 2; ++kk) {
                short8 bv = *(const short8*)((const char*)&lV[cur][0]
                             + (n * 16 + lr) * 128 + (((kk * 4 + lk) ^ (lr & 7)) << 4));
                accO[n] = __builtin_amdgcn_mfma_f32_16x16x32_bf16(ap[kk], bv, accO[n], 0, 0, 0);
            }

        __syncthreads();   // drains vmcnt (next tile landed) + fences buffer reuse
    }

    if (half < 0) {
        // single: normalize and store bf16 into pre_o [4096][1024]
        #pragma unroll
        for (int r = 0; r < 4; ++r) {
            int qrow = q0 + w * 16 + lk * 4 + r;
            float inv = 1.0f / lst[r];
            #pragma unroll
            for (int n = 0; n < 4; ++n)
                pre_o[(long)(b * 2048 + qrow) * 1024 + h * 64 + n * 16 + lr] =
                    f2bf(accO[n][r] * inv);
        }
    } else {
        // split half: write unnormalized partials (fp32 U, m, l)
        const int g2 = ((Q - 20) * 32 + bh) * 2 + half;
        float* U  = pO  + (long)g2 * 4096;
        float* ML = pML + (long)g2 * 128;
        #pragma unroll
        for (int r = 0; r < 4; ++r) {
            int row = w * 16 + lk * 4 + r;
            #pragma unroll
            for (int n = 0; n < 4; ++n)
                U[row * 64 + n * 16 + lr] = accO[n][r];
            if (lr == 0) { ML[row * 2] = mst[r]; ML[row * 2 + 1] = lst[r]; }
        }
    }
}

// ---------------------------------------------------------------------------
// merge the two KV-halves for Q-tiles 20..31: standard flash combine.
__global__ __launch_bounds__(256)
void attn_combine(const float* __restrict__ pO, const float* __restrict__ pML,
                  short* __restrict__ pre_o) {
    const int g = blockIdx.x;                 // 0..383
    const int Q = 20 + (g >> 5), bh = g & 31, b = bh >> 4, h = bh & 15;
    const int t = threadIdx.x;
    const int row = t >> 2, d0 = (t & 3) * 16;
    const float* ML0 = pML + ((long)(g * 2 + 0)) * 128 + row * 2;
    const float* ML1 = pML + ((long)(g * 2 + 1)) * 128 + row * 2;
    float m0 = ML0[0], l0 = ML0[1], m1 = ML1[0], l1 = ML1[1];
    float m = fmaxf(m0, m1);
    float e0 = __expf(m0 - m), e1 = __expf(m1 - m);
    float inv = 1.0f / (l0 * e0 + l1 * e1);
    const float* U0 = pO + ((long)(g * 2 + 0)) * 4096 + row * 64 + d0;
    const float* U1 = pO + ((long)(g * 2 + 1)) * 4096 + row * 64 + d0;
    long out = ((long)(b * 2048 + Q * 64 + row)) * 1024 + h * 64 + d0;
    #pragma unroll
    for (int j = 0; j < 16; j += 4) {
        f32x4 a = *(const f32x4*)&U0[j];
        f32x4 c = *(const f32x4*)&U1[j];
        #pragma unroll
        for (int e = 0; e < 4; ++e)
            pre_o[out + j + e] = f2bf((a[e] * e0 + c[e] * e1) * inv);
    }
}

// ---------------------------------------------------------------------------
extern "C" void kernel_launch(void* const* d_in, const int* in_sizes, int n_in,
                              void* d_out, int out_size, void* d_ws, size_t ws_size,
                              hipStream_t stream) {
    const float* x    = (const float*)d_in[0];   // [2,2048,1024]
    const float* Wqkv = (const float*)d_in[1];   // [1024,3072]
    const float* bqkv = (const float*)d_in[2];   // [3072]
    const float* Wo   = (const float*)d_in[3];   // [1024,1024]
    const float* bo   = (const float*)d_in[4];   // [1024]
    float* out = (float*)d_out;                  // [2,2048,1024] fp32

    char* ws = (char*)d_ws;
    short* xb    = (short*)(ws);                       // 4096*1024   bf16 (8 MB)
    short* wqkvT = (short*)(ws + (8L  << 20));         // 3072*1024   (6 MB)
    short* woT   = (short*)(ws + (14L << 20));         // 1024*1024   (2 MB)
    short* qkv   = (short*)(ws + (16L << 20));         // 4096*3072   (24 MB)
    short* vt    = (short*)(ws + (40L << 20));         // 32*64*2048  (8 MB)
    short* preo  = (short*)(ws + (48L << 20));         // 4096*1024   (8 MB)
    // split-K partials overlay xb+wqkvT (dead during attention):
    float* pO    = (float*)(ws);                       // 384*2*4096 f32 (12.6 MB)
    float* pML   = (float*)(ws + 12779520L);           // 384*2*64*2 f32 (0.4 MB) -> ends < 14 MB

    convert_x<<<4096, 256, 0, stream>>>(x, xb, 4096 * 1024 / 4);
    transpose_conv<<<dim3(48, 16), 256, 0, stream>>>(Wqkv, wqkvT, 1024, 3072);
    transpose_conv<<<dim3(16, 16), 256, 0, stream>>>(Wo, woT, 1024, 1024);
    gemm_bt<0, 1><<<dim3(24, 32), 256, 0, stream>>>(xb, wqkvT, bqkv, qkv, 4096, 3072, 1024);
    build_vt<<<dim3(32, 32), 256, 0, stream>>>(qkv, vt);
    attn_kernel<<<dim3(32, 44), 256, 0, stream>>>(qkv, vt, preo, pO, pML);
    attn_combine<<<384, 256, 0, stream>>>(pO, pML, preo);
    gemm_bt<1, 0><<<dim3(8, 32), 256, 0, stream>>>(preo, woT, bo, out, 4096, 1024, 1024);
}